// Round 6
// baseline (948.975 us; speedup 1.0000x reference)
//
#include <hip/hip_runtime.h>
#include <cstdint>
#include <cstddef>

#define N_E    4096
#define NCOL   4097      // emb rows (n_e + 1)
#define DEMB   512
#define BROWS  16384     // 32 * 512 flattened key_soft rows
#define TLEN   512
#define BB     32
#define NTM    128       // m tiles (16384/128)
#define NTN    33        // n tiles (ceil(4097/128))
#define NWG    (NTM*NTN) // 4224, divisible by 8 -> XCD swizzle bijective

typedef __attribute__((ext_vector_type(8))) short short8;
typedef __attribute__((ext_vector_type(4))) float f4;

// ---------------- workspace layout (bytes, ~17.3 MB total) ----------------
#define WS_KSQ   0                            // float [16384]
#define WS_ESQ   (WS_KSQ + BROWS*4)           // float [4160]
#define WS_PMVB  (WS_ESQ + 4160*4)            // float [33][16384] per-block argmin val
#define WS_PMIB  (WS_PMVB + NTN*BROWS*4)      // int   [33][16384] per-block argmin idx
#define WS_DFB   (WS_PMIB + NTN*BROWS*4)      // float [33][16384] d at col nt*128
#define WS_DLB   (WS_DFB + NTN*BROWS*4)       // float [33][16384] d at col nt*128+127
#define WS_PMVF  (WS_DLB + NTN*BROWS*4)       // float [16384]
#define WS_PMIF  (WS_PMVF + BROWS*4)          // int   [16384]
#define WS_ENC   (WS_PMIF + BROWS*4)          // int   [16384]
#define WS_VMAX  (WS_ENC + BROWS*4)           // int (padded 512)
#define WS_MOVE  (WS_VMAX + 512)              // uint8 [16384][512]

// packed bf16(RNE) pair: h = {bf16(x1),bf16(x0)}, l = bf16 pair of residuals
__device__ __forceinline__ void cvtpair(float x0, float x1, unsigned int& h, unsigned int& l) {
    asm("v_cvt_pk_bf16_f32 %0, %1, %2" : "=v"(h) : "v"(x0), "v"(x1));
    float h0 = __uint_as_float(h << 16);
    float h1 = __uint_as_float(h & 0xFFFF0000u);
    float l0 = x0 - h0, l1 = x1 - h1;
    asm("v_cvt_pk_bf16_f32 %0, %1, %2" : "=v"(l) : "v"(l0), "v"(l1));
}

// ---------------- K0: squared norms ----------------
__global__ __launch_bounds__(256) void k_sq(const float* __restrict__ ks,
                                            const float* __restrict__ emb,
                                            float* __restrict__ ksq,
                                            float* __restrict__ esq) {
    const int w = threadIdx.x >> 6, lane = threadIdx.x & 63;
    const int row = blockIdx.x * 4 + w;
    if (row >= BROWS + NCOL) return;
    const float* src = (row < BROWS) ? (ks + (size_t)row * DEMB)
                                     : (emb + (size_t)(row - BROWS) * DEMB);
    float4 v1 = *(const float4*)(src + lane * 8);
    float4 v2 = *(const float4*)(src + lane * 8 + 4);
    float s = v1.x*v1.x + v1.y*v1.y + v1.z*v1.z + v1.w*v1.w
            + v2.x*v2.x + v2.y*v2.y + v2.z*v2.z + v2.w*v2.w;
    #pragma unroll
    for (int off = 32; off; off >>= 1) s += __shfl_down(s, off, 64);
    if (lane == 0) {
        if (row < BROWS) ksq[row] = s;
        else             esq[row - BROWS] = s;
    }
}

// ---------------- K1: bf16-3-split MFMA distance GEMM ----------------
// dot = Ahi*Bhi + Ahi*Blo + Alo*Bhi (fp32 MFMA accumulate, 16x16x32).
// 128x128 tile, 4 waves (2m x 2n). Fragment-linear LDS (conflict-free reads
// AND writes), single-buffered (32KB -> 4 blocks/CU), reg-prefetch of next tile.
__global__ __launch_bounds__(256, 4) void k_dist(const float* __restrict__ ks,
                                                 const float* __restrict__ emb,
                                                 const float* __restrict__ ksq,
                                                 const float* __restrict__ esq,
                                                 float* __restrict__ pminvB,
                                                 int*   __restrict__ pminiB,
                                                 float* __restrict__ dfB,
                                                 float* __restrict__ dlB,
                                                 unsigned short* __restrict__ mb16) {
    const int t   = threadIdx.x;
    const int bid = blockIdx.x;
    const int swz = (bid & 7) * (NWG / 8) + (bid >> 3);   // XCD-chunked swizzle
    const int mt  = swz / NTN, nt = swz % NTN;
    const int row0 = mt * 128, n0 = nt * 128;

    // fragment-linear LDS: matrix m, chunk c (16B) at lds4[m][c*8 shorts]
    // c = rb*64 + lq*16 + lr  <->  row = rb*16+lr (0..127), k-elems lq*8..+8
    __shared__ short lds4[4][4096];   // Ahi, Alo, Bhi, Blo : 8KB each

    // staging: thread t produces chunks {t, t+256} of all four matrices
    const int r0 = ((t >> 6) << 4) + (t & 15);   // row of chunk t (chunk t+256 = +64)
    const int kq = ((t >> 4) & 3) * 8;           // k-offset (floats)
    const float* apA  = ks  + (size_t)(row0 + r0)      * DEMB + kq;
    const float* apA2 = ks  + (size_t)(row0 + r0 + 64) * DEMB + kq;
    const float* apB  = emb + (size_t)min(n0 + r0,      NCOL - 1) * DEMB + kq;
    const float* apB2 = emb + (size_t)min(n0 + r0 + 64, NCOL - 1) * DEMB + kq;
    const int w0 = t * 8, w1 = (t + 256) * 8;    // LDS shorts offsets (linear!)

    // wave / fragment geometry
    const int w = t >> 6, lane = t & 63;
    const int wm = w >> 1, wn = w & 1;
    const int lq = lane >> 4, lr = lane & 15;

    f4 acc[4][4];
    const f4 fz = {0.f, 0.f, 0.f, 0.f};
    #pragma unroll
    for (int i = 0; i < 4; ++i)
        #pragma unroll
        for (int j = 0; j < 4; ++j) acc[i][j] = fz;

    float4 la0, la1, la2, la3, lb0, lb1, lb2, lb3;

    auto do_loads = [&](int s) {
        const float* p;
        p = apA  + s * 32; la0 = *(const float4*)p; la1 = *(const float4*)(p + 4);
        p = apA2 + s * 32; la2 = *(const float4*)p; la3 = *(const float4*)(p + 4);
        p = apB  + s * 32; lb0 = *(const float4*)p; lb1 = *(const float4*)(p + 4);
        p = apB2 + s * 32; lb2 = *(const float4*)p; lb3 = *(const float4*)(p + 4);
    };
    auto do_cw = [&]() {
        unsigned int h0,h1,h2,h3, g0,g1,g2,g3;
        cvtpair(la0.x,la0.y,h0,g0); cvtpair(la0.z,la0.w,h1,g1);
        cvtpair(la1.x,la1.y,h2,g2); cvtpair(la1.z,la1.w,h3,g3);
        *(uint4*)&lds4[0][w0] = (uint4){h0,h1,h2,h3};
        *(uint4*)&lds4[1][w0] = (uint4){g0,g1,g2,g3};
        cvtpair(la2.x,la2.y,h0,g0); cvtpair(la2.z,la2.w,h1,g1);
        cvtpair(la3.x,la3.y,h2,g2); cvtpair(la3.z,la3.w,h3,g3);
        *(uint4*)&lds4[0][w1] = (uint4){h0,h1,h2,h3};
        *(uint4*)&lds4[1][w1] = (uint4){g0,g1,g2,g3};
        cvtpair(lb0.x,lb0.y,h0,g0); cvtpair(lb0.z,lb0.w,h1,g1);
        cvtpair(lb1.x,lb1.y,h2,g2); cvtpair(lb1.z,lb1.w,h3,g3);
        *(uint4*)&lds4[2][w0] = (uint4){h0,h1,h2,h3};
        *(uint4*)&lds4[3][w0] = (uint4){g0,g1,g2,g3};
        cvtpair(lb2.x,lb2.y,h0,g0); cvtpair(lb2.z,lb2.w,h1,g1);
        cvtpair(lb3.x,lb3.y,h2,g2); cvtpair(lb3.z,lb3.w,h3,g3);
        *(uint4*)&lds4[2][w1] = (uint4){h0,h1,h2,h3};
        *(uint4*)&lds4[3][w1] = (uint4){g0,g1,g2,g3};
    };
    auto do_mm = [&]() {
        short8 fAh[4], fAl[4], fBh[4], fBl[4];
        #pragma unroll
        for (int i = 0; i < 4; ++i) {
            const int off = ((wm * 4 + i) * 64 + lane) * 8;   // linear per wave
            fAh[i] = *(const short8*)&lds4[0][off];
            fAl[i] = *(const short8*)&lds4[1][off];
        }
        #pragma unroll
        for (int j = 0; j < 4; ++j) {
            const int off = ((wn * 4 + j) * 64 + lane) * 8;
            fBh[j] = *(const short8*)&lds4[2][off];
            fBl[j] = *(const short8*)&lds4[3][off];
        }
        #pragma unroll
        for (int i = 0; i < 4; ++i)
            #pragma unroll
            for (int j = 0; j < 4; ++j)
                acc[i][j] = __builtin_amdgcn_mfma_f32_16x16x32_bf16(fAh[i], fBh[j], acc[i][j], 0, 0, 0);
        #pragma unroll
        for (int i = 0; i < 4; ++i)
            #pragma unroll
            for (int j = 0; j < 4; ++j)
                acc[i][j] = __builtin_amdgcn_mfma_f32_16x16x32_bf16(fAh[i], fBl[j], acc[i][j], 0, 0, 0);
        #pragma unroll
        for (int i = 0; i < 4; ++i)
            #pragma unroll
            for (int j = 0; j < 4; ++j)
                acc[i][j] = __builtin_amdgcn_mfma_f32_16x16x32_bf16(fAl[i], fBh[j], acc[i][j], 0, 0, 0);
    };

    // main loop: single LDS buffer, 2 barriers/tile; next-tile global loads
    // issue before do_mm so memory latency hides under 48 MFMAs x 4 waves.
    do_loads(0);
    for (int s = 0; s < 16; ++s) {
        __syncthreads();                  // prior mm done reading LDS
        do_cw();
        __syncthreads();                  // tile visible to all waves
        if (s < 15) do_loads(s + 1);
        do_mm();
    }
    __syncthreads();                      // safe to reuse LDS as scratch

    // LDS scratch (reuses lds4[0], 4KB)
    float* sv0 = (float*)&lds4[0][0];     // [128][2] wave argmin val
    int*   si0 = (int*)(sv0 + 256);       // [128][2] wave argmin idx
    float* sdl = (float*)(si0 + 256);     // [128] wn0 d at col n0+63
    float* sdf = sdl + 128;               // [128] wn1 d at col n0+64
    float* sd0 = sdf + 128;               // [128] wn0 d at col n0     (block dfirst)
    float* sd1 = sd0 + 128;               // [128] wn1 d at col n0+127 (block dlast)

    // ---------------- epilogue: d, movebits, argmin ----------------
    const int colC = n0 + wn * 64;
    float esqv[4];
    #pragma unroll
    for (int j = 0; j < 4; ++j) esqv[j] = esq[min(colC + j*16 + lr, NCOL - 1)];

    #pragma unroll
    for (int i = 0; i < 4; ++i) {
        #pragma unroll
        for (int r2 = 0; r2 < 4; ++r2) {
            const int rowl = wm*64 + i*16 + lq*4 + r2;   // C/D: row=(lane>>4)*4+reg
            const int R = row0 + rowl;
            const float kq2 = ksq[R];
            float dj[4];
            #pragma unroll
            for (int j = 0; j < 4; ++j) {
                float dd = fmaf(-2.f, acc[i][j][r2], kq2 + esqv[j]);
                dj[j] = (colC + j*16 + lr <= NCOL - 1) ? dd : 3.0e38f;
            }
            // wave-level argmin over its 64 cols (lexicographic)
            float bv = dj[0]; int bi = colC + lr;
            #pragma unroll
            for (int j = 1; j < 4; ++j) {
                int c = colC + j*16 + lr;
                if (dj[j] < bv || (dj[j] == bv && c < bi)) { bv = dj[j]; bi = c; }
            }
            #pragma unroll
            for (int off = 1; off < 16; off <<= 1) {
                float ov = __shfl_xor(bv, off, 64); int oi = __shfl_xor(bi, off, 64);
                if (ov < bv || (ov == bv && oi < bi)) { bv = ov; bi = oi; }
            }
            if (lr == 0) {
                sv0[rowl*2 + wn] = bv; si0[rowl*2 + wn] = bi;
                if (wn == 1) sdf[rowl] = dj[0];
                else         sd0[rowl] = dj[0];
            }
            if (lr == 15) {
                if (wn == 0) sdl[rowl] = dj[3];
                else         sd1[rowl] = dj[3];
            }
            // move bits: bit p = (d[p-1] > d[p]); wave's first col handled via seams
            #pragma unroll
            for (int j = 0; j < 4; ++j) {
                float left = __shfl_up(dj[j], 1, 64);
                if (j > 0) {
                    float ph = __shfl(dj[j-1], (lane & 48) | 15, 64);
                    if (lr == 0) left = ph;
                }
                bool pred = (lr == 0 && j == 0) ? false : (left > dj[j]);
                unsigned long long bal = __ballot(pred);
                const int Cb = colC + j * 16;
                if (lr == 0 && Cb < 4096)
                    mb16[(size_t)R*256 + (Cb >> 4)] = (unsigned short)((bal >> (lq*16)) & 0xFFFFull);
            }
        }
    }
    __syncthreads();
    if (t < 128) {
        const int R = row0 + t;
        float v0 = sv0[t*2], v1 = sv0[t*2+1];
        int   i0 = si0[t*2], i1 = si0[t*2+1];
        const bool sel = (v1 < v0 || (v1 == v0 && i1 < i0));
        pminvB[nt*BROWS + R] = sel ? v1 : v0;
        pminiB[nt*BROWS + R] = sel ? i1 : i0;
        dfB[nt*BROWS + R] = sd0[t];
        dlB[nt*BROWS + R] = sd1[t];
        if (nt < 32 && sdl[t] > sdf[t]) {            // in-block seam bit p = n0+64
            uint8_t* mbyte = (uint8_t*)mb16 + (size_t)R*512 + 16*nt + 8;
            *mbyte = (uint8_t)(*mbyte | 1u);
        }
    }
}

// ---------------- K2: 33-block argmin reduce + 128-col seam bits ----------
__global__ __launch_bounds__(256) void k_bnd(const float* __restrict__ pminvB,
                                             const int*   __restrict__ pminiB,
                                             const float* __restrict__ dfB,
                                             const float* __restrict__ dlB,
                                             float* __restrict__ pminvF,
                                             int*   __restrict__ pminiF,
                                             uint8_t* __restrict__ movebits) {
    const int w = threadIdx.x >> 6, lane = threadIdx.x & 63;
    const int m = blockIdx.x * 4 + w;
    float bv = 3.0e38f; int bi = 0x7fffffff;
    if (lane < NTN) { bv = pminvB[lane*BROWS + m]; bi = pminiB[lane*BROWS + m]; }
    #pragma unroll
    for (int off = 1; off < 64; off <<= 1) {
        float ov = __shfl_xor(bv, off, 64); int oi = __shfl_xor(bi, off, 64);
        if (ov < bv || (ov == bv && oi < bi)) { bv = ov; bi = oi; }
    }
    if (lane == 0) { pminvF[m] = bv; pminiF[m] = bi; }
    if (lane >= 1 && lane < 32) {   // bit p = 128*lane
        bool b = dlB[(lane-1)*BROWS + m] > dfB[lane*BROWS + m];
        if (b) {
            uint8_t* p = movebits + (size_t)m * 512 + 16 * lane;
            *p = (uint8_t)(*p | 1u);
        }
    }
}

// ---------------- K3: sequential neighbor scan over move bits ----------------
__global__ __launch_bounds__(64) void k_scan(const int* __restrict__ pminiF,
                                             const uint8_t* __restrict__ mask,
                                             const uint8_t* __restrict__ movebits,
                                             int* __restrict__ enc,
                                             int* __restrict__ vmax) {
    const int b = blockIdx.x;
    const int lane = threadIdx.x;
    const int row0 = b * TLEN;

    int j = min(pminiF[row0], N_E - 1);
    if (mask[b]) j = 0;
    const int jstart = j;

    for (int c = 0; c < 8; ++c) {
        const int t = c * 64 + lane;
        const uint32_t* rowp = (const uint32_t*)(movebits + (size_t)(row0 + t) * 512);
        const int D0a = min((j >> 5) & ~3, 120);   // uniform, window in-row
        uint4 wlo = *(const uint4*)(rowp + D0a);
        uint4 whi = *(const uint4*)(rowp + D0a + 4);
        int myenc = j;
        for (int tt = 0; tt < 64; ++tt) {
            const int tglob = c * 64 + tt;
            if (tglob > 0) {
                int q  = j + 1;
                int wi = (q >> 5) - D0a;
                uint32_t sel = wi == 0 ? wlo.x : wi == 1 ? wlo.y : wi == 2 ? wlo.z :
                               wi == 3 ? wlo.w : wi == 4 ? whi.x : wi == 5 ? whi.y :
                               wi == 6 ? whi.z : whi.w;
                uint32_t word = __shfl(sel, tt, 64);
                int bit = (word >> (q & 31)) & 1;
                if (j < N_E - 1) j += bit;
            }
            if (lane == tt) myenc = j;
        }
        enc[row0 + c * 64 + lane] = myenc;
    }
    if (lane == 0) atomicMax(vmax, j - jstart);
}

// ---------------- K4: gathers, losses, outputs ----------------
__global__ __launch_bounds__(256) void k_loss(const float* __restrict__ ks,
                                              const float* __restrict__ emb,
                                              const int*   __restrict__ pminiF,
                                              const int*   __restrict__ enc,
                                              const int*   __restrict__ vmax,
                                              float* __restrict__ out) {
    const int w = threadIdx.x >> 6, lane = threadIdx.x & 63;
    const int row = blockIdx.x * 4 + w;

    float* key_hard = out;
    float* encf     = out + (size_t)BROWS * DEMB;
    float* vout     = encf + BROWS;
    float* lh       = vout + 1;
    float* ln       = lh + BROWS;

    if (blockIdx.x == 0 && threadIdx.x == 0) vout[0] = (float)(*vmax);

    const int j  = enc[row];
    const int jn = min(j + 1, N_E - 1);
    const int mi = pminiF[row];   // unclipped argmin

    const float* ksp = ks  + (size_t)row * DEMB + lane * 8;
    const float* eh  = emb + (size_t)j   * DEMB + lane * 8;
    const float* en  = emb + (size_t)jn  * DEMB + lane * 8;
    const float* em  = emb + (size_t)mi  * DEMB + lane * 8;

    float4 ka = *(const float4*)ksp,     kb = *(const float4*)(ksp + 4);
    float4 ha = *(const float4*)eh,      hb = *(const float4*)(eh + 4);
    float4 na = *(const float4*)en,      nb = *(const float4*)(en + 4);
    float4 ma = *(const float4*)em,      mb = *(const float4*)(em + 4);

    float sh = 0.f, sn = 0.f, sm = 0.f;
    {
        float t;
        t = ka.x-ha.x; sh += t*t;  t = ka.y-ha.y; sh += t*t;
        t = ka.z-ha.z; sh += t*t;  t = ka.w-ha.w; sh += t*t;
        t = kb.x-hb.x; sh += t*t;  t = kb.y-hb.y; sh += t*t;
        t = kb.z-hb.z; sh += t*t;  t = kb.w-hb.w; sh += t*t;
        t = ka.x-na.x; sn += t*t;  t = ka.y-na.y; sn += t*t;
        t = ka.z-na.z; sn += t*t;  t = ka.w-na.w; sn += t*t;
        t = kb.x-nb.x; sn += t*t;  t = kb.y-nb.y; sn += t*t;
        t = kb.z-nb.z; sn += t*t;  t = kb.w-nb.w; sn += t*t;
        t = ka.x-ma.x; sm += t*t;  t = ka.y-ma.y; sm += t*t;
        t = ka.z-ma.z; sm += t*t;  t = ka.w-ma.w; sm += t*t;
        t = kb.x-mb.x; sm += t*t;  t = kb.y-mb.y; sm += t*t;
        t = kb.z-mb.z; sm += t*t;  t = kb.w-mb.w; sm += t*t;
    }
    #pragma unroll
    for (int off = 32; off; off >>= 1) {
        sh += __shfl_down(sh, off, 64);
        sn += __shfl_down(sn, off, 64);
        sm += __shfl_down(sm, off, 64);
    }

    *(float4*)(key_hard + (size_t)row * DEMB + lane * 8)     = ha;
    *(float4*)(key_hard + (size_t)row * DEMB + lane * 8 + 4) = hb;

    if (lane == 0) {
        float bh = sh * 0.2f + sh;
        float bn = sn * 0.2f + sn;
        float lm = sm + sm * 0.2f;
        lh[row]   = bh - (lm < bh ? lm : 0.f);
        ln[row]   = bn - (lm < bn ? lm : 0.f);
        encf[row] = (float)j;
    }
}

// ---------------- launcher ----------------
extern "C" void kernel_launch(void* const* d_in, const int* in_sizes, int n_in,
                              void* d_out, int out_size, void* d_ws, size_t ws_size,
                              hipStream_t stream) {
    const float*   ks   = (const float*)d_in[0];
    const float*   emb  = (const float*)d_in[1];
    const uint8_t* mask = (const uint8_t*)d_in[2];
    float* out = (float*)d_out;
    uint8_t* ws = (uint8_t*)d_ws;

    float* ksq    = (float*)(ws + WS_KSQ);
    float* esq    = (float*)(ws + WS_ESQ);
    float* pminvB = (float*)(ws + WS_PMVB);
    int*   pminiB = (int*)(ws + WS_PMIB);
    float* dfB    = (float*)(ws + WS_DFB);
    float* dlB    = (float*)(ws + WS_DLB);
    float* pminvF = (float*)(ws + WS_PMVF);
    int*   pminiF = (int*)(ws + WS_PMIF);
    int*   enc    = (int*)(ws + WS_ENC);
    int*   vmax   = (int*)(ws + WS_VMAX);
    uint8_t* movebits = ws + WS_MOVE;

    hipMemsetAsync(vmax, 0, 4, stream);
    k_sq  <<<(BROWS + NCOL + 3) / 4, 256, 0, stream>>>(ks, emb, ksq, esq);
    k_dist<<<NWG, 256, 0, stream>>>(ks, emb, ksq, esq, pminvB, pminiB,
                                    dfB, dlB, (unsigned short*)movebits);
    k_bnd <<<BROWS / 4, 256, 0, stream>>>(pminvB, pminiB, dfB, dlB, pminvF, pminiF, movebits);
    k_scan<<<BB, 64, 0, stream>>>(pminiF, mask, movebits, enc, vmax);
    k_loss<<<BROWS / 4, 256, 0, stream>>>(ks, emb, pminiF, enc, vmax, out);
}

// Round 8
// 553.558 us; speedup vs baseline: 1.7143x; 1.7143x over previous
//
#include <hip/hip_runtime.h>
#include <cstdint>
#include <cstddef>

#define N_E    4096
#define NCOL   4097      // emb rows (n_e + 1)
#define DEMB   512
#define BROWS  16384     // 32 * 512 flattened key_soft rows
#define TLEN   512
#define BB     32
#define NTM    128       // m tiles (16384/128)
#define NTN    33        // n tiles (ceil(4097/128))
#define NWG    (NTM*NTN) // 4224, divisible by 8 -> XCD swizzle bijective

typedef __attribute__((ext_vector_type(8))) short short8;
typedef __attribute__((ext_vector_type(4))) float f4;

// ---------------- workspace layout (bytes, ~17.3 MB total) ----------------
#define WS_KSQ   0                            // float [16384]
#define WS_ESQ   (WS_KSQ + BROWS*4)           // float [4160]
#define WS_PMVB  (WS_ESQ + 4160*4)            // float [33][16384] per-block argmin val
#define WS_PMIB  (WS_PMVB + NTN*BROWS*4)      // int   [33][16384] per-block argmin idx
#define WS_DFB   (WS_PMIB + NTN*BROWS*4)      // float [33][16384] d at col nt*128
#define WS_DLB   (WS_DFB + NTN*BROWS*4)       // float [33][16384] d at col nt*128+127
#define WS_PMVF  (WS_DLB + NTN*BROWS*4)       // float [16384]
#define WS_PMIF  (WS_PMVF + BROWS*4)          // int   [16384]
#define WS_ENC   (WS_PMIF + BROWS*4)          // int   [16384]
#define WS_VMAX  (WS_ENC + BROWS*4)           // int (padded 512)
#define WS_MOVE  (WS_VMAX + 512)              // uint8 [16384][512]

// packed bf16(RNE) pair: h = {bf16(x1),bf16(x0)}, l = bf16 pair of residuals
__device__ __forceinline__ void cvtpair(float x0, float x1, unsigned int& h, unsigned int& l) {
    asm("v_cvt_pk_bf16_f32 %0, %1, %2" : "=v"(h) : "v"(x0), "v"(x1));
    float h0 = __uint_as_float(h << 16);
    float h1 = __uint_as_float(h & 0xFFFF0000u);
    float l0 = x0 - h0, l1 = x1 - h1;
    asm("v_cvt_pk_bf16_f32 %0, %1, %2" : "=v"(l) : "v"(l0), "v"(l1));
}

// ---------------- K0: squared norms ----------------
__global__ __launch_bounds__(256) void k_sq(const float* __restrict__ ks,
                                            const float* __restrict__ emb,
                                            float* __restrict__ ksq,
                                            float* __restrict__ esq) {
    const int w = threadIdx.x >> 6, lane = threadIdx.x & 63;
    const int row = blockIdx.x * 4 + w;
    if (row >= BROWS + NCOL) return;
    const float* src = (row < BROWS) ? (ks + (size_t)row * DEMB)
                                     : (emb + (size_t)(row - BROWS) * DEMB);
    float4 v1 = *(const float4*)(src + lane * 8);
    float4 v2 = *(const float4*)(src + lane * 8 + 4);
    float s = v1.x*v1.x + v1.y*v1.y + v1.z*v1.z + v1.w*v1.w
            + v2.x*v2.x + v2.y*v2.y + v2.z*v2.z + v2.w*v2.w;
    #pragma unroll
    for (int off = 32; off; off >>= 1) s += __shfl_down(s, off, 64);
    if (lane == 0) {
        if (row < BROWS) ksq[row] = s;
        else             esq[row - BROWS] = s;
    }
}

// ---------------- K1: bf16-3-split MFMA distance GEMM ----------------
// dot = Ahi*Bhi + Ahi*Blo + Alo*Bhi (fp32 MFMA accumulate, 16x16x32).
// 128x128 tile, 4 waves (2m x 2n). Fragment-linear LDS (conflict-free reads
// AND writes), single-buffered (32KB). launch_bounds(256,3): 170-reg cap
// fits the ~152 live regs (64 acc AGPR + ~88 VGPR) -> NO SPILLS (the (256,4)
// 128-reg cap spilled ~1.5KB/thread -> 1.6GB scratch writes, round-6 regression).
__global__ __launch_bounds__(256, 3) void k_dist(const float* __restrict__ ks,
                                                 const float* __restrict__ emb,
                                                 const float* __restrict__ ksq,
                                                 const float* __restrict__ esq,
                                                 float* __restrict__ pminvB,
                                                 int*   __restrict__ pminiB,
                                                 float* __restrict__ dfB,
                                                 float* __restrict__ dlB,
                                                 unsigned short* __restrict__ mb16) {
    const int t   = threadIdx.x;
    const int bid = blockIdx.x;
    const int swz = (bid & 7) * (NWG / 8) + (bid >> 3);   // XCD-chunked swizzle
    const int mt  = swz / NTN, nt = swz % NTN;
    const int row0 = mt * 128, n0 = nt * 128;

    // fragment-linear LDS: matrix m, chunk c (16B) at lds4[m][c*8 shorts]
    // c = rb*64 + lq*16 + lr  <->  row = rb*16+lr (0..127), k-elems lq*8..+8
    __shared__ short lds4[4][4096];   // Ahi, Alo, Bhi, Blo : 8KB each

    // staging: thread t produces chunks {t, t+256} of all four matrices
    const int r0 = ((t >> 6) << 4) + (t & 15);   // row of chunk t (chunk t+256 = +64)
    const int kq = ((t >> 4) & 3) * 8;           // k-offset (floats)
    const float* apA  = ks  + (size_t)(row0 + r0)      * DEMB + kq;
    const float* apA2 = ks  + (size_t)(row0 + r0 + 64) * DEMB + kq;
    const float* apB  = emb + (size_t)min(n0 + r0,      NCOL - 1) * DEMB + kq;
    const float* apB2 = emb + (size_t)min(n0 + r0 + 64, NCOL - 1) * DEMB + kq;
    const int w0 = t * 8, w1 = (t + 256) * 8;    // LDS shorts offsets (linear!)

    // wave / fragment geometry
    const int w = t >> 6, lane = t & 63;
    const int wm = w >> 1, wn = w & 1;
    const int lq = lane >> 4, lr = lane & 15;

    f4 acc[4][4];
    const f4 fz = {0.f, 0.f, 0.f, 0.f};
    #pragma unroll
    for (int i = 0; i < 4; ++i)
        #pragma unroll
        for (int j = 0; j < 4; ++j) acc[i][j] = fz;

    float4 la0, la1, la2, la3, lb0, lb1, lb2, lb3;

    auto do_loads = [&](int s) {
        const float* p;
        p = apA  + s * 32; la0 = *(const float4*)p; la1 = *(const float4*)(p + 4);
        p = apA2 + s * 32; la2 = *(const float4*)p; la3 = *(const float4*)(p + 4);
        p = apB  + s * 32; lb0 = *(const float4*)p; lb1 = *(const float4*)(p + 4);
        p = apB2 + s * 32; lb2 = *(const float4*)p; lb3 = *(const float4*)(p + 4);
    };
    auto do_cw = [&]() {
        unsigned int h0,h1,h2,h3, g0,g1,g2,g3;
        cvtpair(la0.x,la0.y,h0,g0); cvtpair(la0.z,la0.w,h1,g1);
        cvtpair(la1.x,la1.y,h2,g2); cvtpair(la1.z,la1.w,h3,g3);
        *(uint4*)&lds4[0][w0] = (uint4){h0,h1,h2,h3};
        *(uint4*)&lds4[1][w0] = (uint4){g0,g1,g2,g3};
        cvtpair(la2.x,la2.y,h0,g0); cvtpair(la2.z,la2.w,h1,g1);
        cvtpair(la3.x,la3.y,h2,g2); cvtpair(la3.z,la3.w,h3,g3);
        *(uint4*)&lds4[0][w1] = (uint4){h0,h1,h2,h3};
        *(uint4*)&lds4[1][w1] = (uint4){g0,g1,g2,g3};
        cvtpair(lb0.x,lb0.y,h0,g0); cvtpair(lb0.z,lb0.w,h1,g1);
        cvtpair(lb1.x,lb1.y,h2,g2); cvtpair(lb1.z,lb1.w,h3,g3);
        *(uint4*)&lds4[2][w0] = (uint4){h0,h1,h2,h3};
        *(uint4*)&lds4[3][w0] = (uint4){g0,g1,g2,g3};
        cvtpair(lb2.x,lb2.y,h0,g0); cvtpair(lb2.z,lb2.w,h1,g1);
        cvtpair(lb3.x,lb3.y,h2,g2); cvtpair(lb3.z,lb3.w,h3,g3);
        *(uint4*)&lds4[2][w1] = (uint4){h0,h1,h2,h3};
        *(uint4*)&lds4[3][w1] = (uint4){g0,g1,g2,g3};
    };
    auto do_mm = [&]() {
        short8 fAh[4], fAl[4], fBh[4], fBl[4];
        #pragma unroll
        for (int i = 0; i < 4; ++i) {
            const int off = ((wm * 4 + i) * 64 + lane) * 8;   // linear per wave
            fAh[i] = *(const short8*)&lds4[0][off];
            fAl[i] = *(const short8*)&lds4[1][off];
        }
        #pragma unroll
        for (int j = 0; j < 4; ++j) {
            const int off = ((wn * 4 + j) * 64 + lane) * 8;
            fBh[j] = *(const short8*)&lds4[2][off];
            fBl[j] = *(const short8*)&lds4[3][off];
        }
        #pragma unroll
        for (int i = 0; i < 4; ++i)
            #pragma unroll
            for (int j = 0; j < 4; ++j)
                acc[i][j] = __builtin_amdgcn_mfma_f32_16x16x32_bf16(fAh[i], fBh[j], acc[i][j], 0, 0, 0);
        #pragma unroll
        for (int i = 0; i < 4; ++i)
            #pragma unroll
            for (int j = 0; j < 4; ++j)
                acc[i][j] = __builtin_amdgcn_mfma_f32_16x16x32_bf16(fAh[i], fBl[j], acc[i][j], 0, 0, 0);
        #pragma unroll
        for (int i = 0; i < 4; ++i)
            #pragma unroll
            for (int j = 0; j < 4; ++j)
                acc[i][j] = __builtin_amdgcn_mfma_f32_16x16x32_bf16(fAl[i], fBh[j], acc[i][j], 0, 0, 0);
    };

    // main loop: single LDS buffer, 2 barriers/tile; next-tile global loads
    // issue before do_mm so memory latency hides under 48 MFMAs x 4 waves.
    do_loads(0);
    for (int s = 0; s < 16; ++s) {
        __syncthreads();                  // prior mm done reading LDS
        do_cw();
        __syncthreads();                  // tile visible to all waves
        if (s < 15) do_loads(s + 1);
        do_mm();
    }
    __syncthreads();                      // safe to reuse LDS as scratch

    // LDS scratch (reuses lds4[0], 4KB)
    float* sv0 = (float*)&lds4[0][0];     // [128][2] wave argmin val
    int*   si0 = (int*)(sv0 + 256);       // [128][2] wave argmin idx
    float* sdl = (float*)(si0 + 256);     // [128] wn0 d at col n0+63
    float* sdf = sdl + 128;               // [128] wn1 d at col n0+64
    float* sd0 = sdf + 128;               // [128] wn0 d at col n0     (block dfirst)
    float* sd1 = sd0 + 128;               // [128] wn1 d at col n0+127 (block dlast)

    // ---------------- epilogue: d, movebits, argmin ----------------
    const int colC = n0 + wn * 64;
    float esqv[4];
    #pragma unroll
    for (int j = 0; j < 4; ++j) esqv[j] = esq[min(colC + j*16 + lr, NCOL - 1)];

    #pragma unroll
    for (int i = 0; i < 4; ++i) {
        #pragma unroll
        for (int r2 = 0; r2 < 4; ++r2) {
            const int rowl = wm*64 + i*16 + lq*4 + r2;   // C/D: row=(lane>>4)*4+reg
            const int R = row0 + rowl;
            const float kq2 = ksq[R];
            float dj[4];
            #pragma unroll
            for (int j = 0; j < 4; ++j) {
                float dd = fmaf(-2.f, acc[i][j][r2], kq2 + esqv[j]);
                dj[j] = (colC + j*16 + lr <= NCOL - 1) ? dd : 3.0e38f;
            }
            // wave-level argmin over its 64 cols (lexicographic)
            float bv = dj[0]; int bi = colC + lr;
            #pragma unroll
            for (int j = 1; j < 4; ++j) {
                int c = colC + j*16 + lr;
                if (dj[j] < bv || (dj[j] == bv && c < bi)) { bv = dj[j]; bi = c; }
            }
            #pragma unroll
            for (int off = 1; off < 16; off <<= 1) {
                float ov = __shfl_xor(bv, off, 64); int oi = __shfl_xor(bi, off, 64);
                if (ov < bv || (ov == bv && oi < bi)) { bv = ov; bi = oi; }
            }
            if (lr == 0) {
                sv0[rowl*2 + wn] = bv; si0[rowl*2 + wn] = bi;
                if (wn == 1) sdf[rowl] = dj[0];
                else         sd0[rowl] = dj[0];
            }
            if (lr == 15) {
                if (wn == 0) sdl[rowl] = dj[3];
                else         sd1[rowl] = dj[3];
            }
            // move bits: bit p = (d[p-1] > d[p]); wave's first col handled via seams
            #pragma unroll
            for (int j = 0; j < 4; ++j) {
                float left = __shfl_up(dj[j], 1, 64);
                if (j > 0) {
                    float ph = __shfl(dj[j-1], (lane & 48) | 15, 64);
                    if (lr == 0) left = ph;
                }
                bool pred = (lr == 0 && j == 0) ? false : (left > dj[j]);
                unsigned long long bal = __ballot(pred);
                const int Cb = colC + j * 16;
                if (lr == 0 && Cb < 4096)
                    mb16[(size_t)R*256 + (Cb >> 4)] = (unsigned short)((bal >> (lq*16)) & 0xFFFFull);
            }
        }
    }
    __syncthreads();
    if (t < 128) {
        const int R = row0 + t;
        float v0 = sv0[t*2], v1 = sv0[t*2+1];
        int   i0 = si0[t*2], i1 = si0[t*2+1];
        const bool sel = (v1 < v0 || (v1 == v0 && i1 < i0));
        pminvB[nt*BROWS + R] = sel ? v1 : v0;
        pminiB[nt*BROWS + R] = sel ? i1 : i0;
        dfB[nt*BROWS + R] = sd0[t];
        dlB[nt*BROWS + R] = sd1[t];
        if (nt < 32 && sdl[t] > sdf[t]) {            // in-block seam bit p = n0+64
            uint8_t* mbyte = (uint8_t*)mb16 + (size_t)R*512 + 16*nt + 8;
            *mbyte = (uint8_t)(*mbyte | 1u);
        }
    }
}

// ---------------- K2: 33-block argmin reduce + 128-col seam bits ----------
__global__ __launch_bounds__(256) void k_bnd(const float* __restrict__ pminvB,
                                             const int*   __restrict__ pminiB,
                                             const float* __restrict__ dfB,
                                             const float* __restrict__ dlB,
                                             float* __restrict__ pminvF,
                                             int*   __restrict__ pminiF,
                                             uint8_t* __restrict__ movebits) {
    const int w = threadIdx.x >> 6, lane = threadIdx.x & 63;
    const int m = blockIdx.x * 4 + w;
    float bv = 3.0e38f; int bi = 0x7fffffff;
    if (lane < NTN) { bv = pminvB[lane*BROWS + m]; bi = pminiB[lane*BROWS + m]; }
    #pragma unroll
    for (int off = 1; off < 64; off <<= 1) {
        float ov = __shfl_xor(bv, off, 64); int oi = __shfl_xor(bi, off, 64);
        if (ov < bv || (ov == bv && oi < bi)) { bv = ov; bi = oi; }
    }
    if (lane == 0) { pminvF[m] = bv; pminiF[m] = bi; }
    if (lane >= 1 && lane < 32) {   // bit p = 128*lane
        bool b = dlB[(lane-1)*BROWS + m] > dfB[lane*BROWS + m];
        if (b) {
            uint8_t* p = movebits + (size_t)m * 512 + 16 * lane;
            *p = (uint8_t)(*p | 1u);
        }
    }
}

// ---------------- K3: sequential neighbor scan over move bits ----------------
__global__ __launch_bounds__(64) void k_scan(const int* __restrict__ pminiF,
                                             const uint8_t* __restrict__ mask,
                                             const uint8_t* __restrict__ movebits,
                                             int* __restrict__ enc,
                                             int* __restrict__ vmax) {
    const int b = blockIdx.x;
    const int lane = threadIdx.x;
    const int row0 = b * TLEN;

    int j = min(pminiF[row0], N_E - 1);
    if (mask[b]) j = 0;
    const int jstart = j;

    for (int c = 0; c < 8; ++c) {
        const int t = c * 64 + lane;
        const uint32_t* rowp = (const uint32_t*)(movebits + (size_t)(row0 + t) * 512);
        const int D0a = min((j >> 5) & ~3, 120);   // uniform, window in-row
        uint4 wlo = *(const uint4*)(rowp + D0a);
        uint4 whi = *(const uint4*)(rowp + D0a + 4);
        int myenc = j;
        for (int tt = 0; tt < 64; ++tt) {
            const int tglob = c * 64 + tt;
            if (tglob > 0) {
                int q  = j + 1;
                int wi = (q >> 5) - D0a;
                uint32_t sel = wi == 0 ? wlo.x : wi == 1 ? wlo.y : wi == 2 ? wlo.z :
                               wi == 3 ? wlo.w : wi == 4 ? whi.x : wi == 5 ? whi.y :
                               wi == 6 ? whi.z : whi.w;
                uint32_t word = __shfl(sel, tt, 64);
                int bit = (word >> (q & 31)) & 1;
                if (j < N_E - 1) j += bit;
            }
            if (lane == tt) myenc = j;
        }
        enc[row0 + c * 64 + lane] = myenc;
    }
    if (lane == 0) atomicMax(vmax, j - jstart);
}

// ---------------- K4: gathers, losses, outputs ----------------
__global__ __launch_bounds__(256) void k_loss(const float* __restrict__ ks,
                                              const float* __restrict__ emb,
                                              const int*   __restrict__ pminiF,
                                              const int*   __restrict__ enc,
                                              const int*   __restrict__ vmax,
                                              float* __restrict__ out) {
    const int w = threadIdx.x >> 6, lane = threadIdx.x & 63;
    const int row = blockIdx.x * 4 + w;

    float* key_hard = out;
    float* encf     = out + (size_t)BROWS * DEMB;
    float* vout     = encf + BROWS;
    float* lh       = vout + 1;
    float* ln       = lh + BROWS;

    if (blockIdx.x == 0 && threadIdx.x == 0) vout[0] = (float)(*vmax);

    const int j  = enc[row];
    const int jn = min(j + 1, N_E - 1);
    const int mi = pminiF[row];   // unclipped argmin

    const float* ksp = ks  + (size_t)row * DEMB + lane * 8;
    const float* eh  = emb + (size_t)j   * DEMB + lane * 8;
    const float* en  = emb + (size_t)jn  * DEMB + lane * 8;
    const float* em  = emb + (size_t)mi  * DEMB + lane * 8;

    float4 ka = *(const float4*)ksp,     kb = *(const float4*)(ksp + 4);
    float4 ha = *(const float4*)eh,      hb = *(const float4*)(eh + 4);
    float4 na = *(const float4*)en,      nb = *(const float4*)(en + 4);
    float4 ma = *(const float4*)em,      mb = *(const float4*)(em + 4);

    float sh = 0.f, sn = 0.f, sm = 0.f;
    {
        float t;
        t = ka.x-ha.x; sh += t*t;  t = ka.y-ha.y; sh += t*t;
        t = ka.z-ha.z; sh += t*t;  t = ka.w-ha.w; sh += t*t;
        t = kb.x-hb.x; sh += t*t;  t = kb.y-hb.y; sh += t*t;
        t = kb.z-hb.z; sh += t*t;  t = kb.w-hb.w; sh += t*t;
        t = ka.x-na.x; sn += t*t;  t = ka.y-na.y; sn += t*t;
        t = ka.z-na.z; sn += t*t;  t = ka.w-na.w; sn += t*t;
        t = kb.x-nb.x; sn += t*t;  t = kb.y-nb.y; sn += t*t;
        t = kb.z-nb.z; sn += t*t;  t = kb.w-nb.w; sn += t*t;
        t = ka.x-ma.x; sm += t*t;  t = ka.y-ma.y; sm += t*t;
        t = ka.z-ma.z; sm += t*t;  t = ka.w-ma.w; sm += t*t;
        t = kb.x-mb.x; sm += t*t;  t = kb.y-mb.y; sm += t*t;
        t = kb.z-mb.z; sm += t*t;  t = kb.w-mb.w; sm += t*t;
    }
    #pragma unroll
    for (int off = 32; off; off >>= 1) {
        sh += __shfl_down(sh, off, 64);
        sn += __shfl_down(sn, off, 64);
        sm += __shfl_down(sm, off, 64);
    }

    *(float4*)(key_hard + (size_t)row * DEMB + lane * 8)     = ha;
    *(float4*)(key_hard + (size_t)row * DEMB + lane * 8 + 4) = hb;

    if (lane == 0) {
        float bh = sh * 0.2f + sh;
        float bn = sn * 0.2f + sn;
        float lm = sm + sm * 0.2f;
        lh[row]   = bh - (lm < bh ? lm : 0.f);
        ln[row]   = bn - (lm < bn ? lm : 0.f);
        encf[row] = (float)j;
    }
}

// ---------------- launcher ----------------
extern "C" void kernel_launch(void* const* d_in, const int* in_sizes, int n_in,
                              void* d_out, int out_size, void* d_ws, size_t ws_size,
                              hipStream_t stream) {
    const float*   ks   = (const float*)d_in[0];
    const float*   emb  = (const float*)d_in[1];
    const uint8_t* mask = (const uint8_t*)d_in[2];
    float* out = (float*)d_out;
    uint8_t* ws = (uint8_t*)d_ws;

    float* ksq    = (float*)(ws + WS_KSQ);
    float* esq    = (float*)(ws + WS_ESQ);
    float* pminvB = (float*)(ws + WS_PMVB);
    int*   pminiB = (int*)(ws + WS_PMIB);
    float* dfB    = (float*)(ws + WS_DFB);
    float* dlB    = (float*)(ws + WS_DLB);
    float* pminvF = (float*)(ws + WS_PMVF);
    int*   pminiF = (int*)(ws + WS_PMIF);
    int*   enc    = (int*)(ws + WS_ENC);
    int*   vmax   = (int*)(ws + WS_VMAX);
    uint8_t* movebits = ws + WS_MOVE;

    hipMemsetAsync(vmax, 0, 4, stream);
    k_sq  <<<(BROWS + NCOL + 3) / 4, 256, 0, stream>>>(ks, emb, ksq, esq);
    k_dist<<<NWG, 256, 0, stream>>>(ks, emb, ksq, esq, pminvB, pminiB,
                                    dfB, dlB, (unsigned short*)movebits);
    k_bnd <<<BROWS / 4, 256, 0, stream>>>(pminvB, pminiB, dfB, dlB, pminvF, pminiF, movebits);
    k_scan<<<BB, 64, 0, stream>>>(pminiF, mask, movebits, enc, vmax);
    k_loss<<<BROWS / 4, 256, 0, stream>>>(ks, emb, pminiF, enc, vmax, out);
}